// Round 4
// baseline (643.484 us; speedup 1.0000x reference)
//
#include <hip/hip_runtime.h>
#include <math.h>

#define HD 128

union F4 { float4 v; float f[4]; };

// ---------------- CSR build ----------------
__global__ void k_count(const int* __restrict__ dst, int* __restrict__ counts, int E){
  int e = blockIdx.x*256 + threadIdx.x;
  if (e < E) atomicAdd(&counts[dst[e]], 1);
}

__global__ void k_scan_block(const int* __restrict__ counts, int* __restrict__ scanTmp,
                             int* __restrict__ blockSums, int n){
  __shared__ int sm[256];
  int i = blockIdx.x*256 + threadIdx.x;
  int v = (i<n)?counts[i]:0;
  sm[threadIdx.x]=v; __syncthreads();
  for (int ofs=1; ofs<256; ofs<<=1){
    int t = (threadIdx.x>=ofs)?sm[threadIdx.x-ofs]:0;
    __syncthreads();
    sm[threadIdx.x]+=t;
    __syncthreads();
  }
  if (i<n) scanTmp[i]=sm[threadIdx.x];
  if (threadIdx.x==255) blockSums[blockIdx.x]=sm[255];
}

__global__ void k_scan_top(int* __restrict__ blockSums, int nb){
  __shared__ int sm[1024];
  int v = ((int)threadIdx.x<nb)?blockSums[threadIdx.x]:0;
  sm[threadIdx.x]=v; __syncthreads();
  for (int ofs=1; ofs<1024; ofs<<=1){
    int t = ((int)threadIdx.x>=ofs)?sm[threadIdx.x-ofs]:0;
    __syncthreads();
    sm[threadIdx.x]+=t;
    __syncthreads();
  }
  if ((int)threadIdx.x<nb) blockSums[threadIdx.x] = sm[threadIdx.x]-v; // exclusive
}

__global__ void k_scan_fin(const int* __restrict__ scanTmp, const int* __restrict__ blockSums,
                           const int* __restrict__ counts,
                           int* __restrict__ row_ptr, int* __restrict__ cursors, int n){
  int i = blockIdx.x*256 + threadIdx.x;
  if (i<n){
    int incl = scanTmp[i] + blockSums[blockIdx.x];
    row_ptr[i+1] = incl;
    cursors[i] = incl - counts[i];
  }
  if (i==0) row_ptr[0]=0;
}

// scatter edges into CSR order, payload packed as one 16B record:
// {src, etype, norm_bits, 0} -> single dwordx4 load in the edge loop.
__global__ void k_scatter(const int* __restrict__ dst, const int* __restrict__ src,
                          const int* __restrict__ et, const float* __restrict__ norm,
                          int* __restrict__ cursors, int4* __restrict__ pay, int E){
  int e = blockIdx.x*256 + threadIdx.x;
  if (e<E){
    int p = atomicAdd(&cursors[dst[e]],1);
    pay[p] = make_int4(src[e], et[e], __float_as_int(norm[e]), 0);
  }
}

// ---------------- gather h0 = emb[node_ids] ----------------
__global__ void k_gather(const int* __restrict__ ids, const float4* __restrict__ emb4,
                         float4* __restrict__ h0, int nf4){
  int i = blockIdx.x*256+threadIdx.x;
  if (i<nf4){
    int row = i>>5, c = i&31;
    h0[i] = emb4[ids[row]*32 + c];
  }
}

// ---------------- edge aggregation (gather-CSR, one wave per dst row) ----------------
// Payload software-pipelined one edge ahead: per-iteration exposed latency is
// max(h,W) instead of payload + max(h,W).
__global__ __launch_bounds__(256)
void k_edge1(const int* __restrict__ row_ptr, const int4* __restrict__ pay,
             const float* __restrict__ h, const float* __restrict__ W,
             float* __restrict__ agg, int Nn){
  int wid = (blockIdx.x*256 + threadIdx.x)>>6;
  int lane = threadIdx.x & 63;
  if (wid >= Nn) return;
  int e0 = row_ptr[wid], e1 = row_ptr[wid+1];
  int b0 = lane>>2, o = lane&3;
  float acc0=0.f, acc1=0.f;
  int4 pl;
  if (e0 < e1) pl = pay[e0];
  for (int e=e0; e<e1; ++e){
    int4 nx = (e+1<e1) ? pay[e+1] : pl;
    int s = pl.x; int r = pl.y; float nm = __int_as_float(pl.z);
    const float* hp = &h[s*HD];
    const float* w  = &W[r*512];
    float4 hA = *(const float4*)&hp[b0*4];
    float4 hB = *(const float4*)&hp[(b0+16)*4];
    const float* wA = &w[b0*16 + o];
    const float* wB = &w[(b0+16)*16 + o];
    float m0 = hA.x*wA[0] + hA.y*wA[4] + hA.z*wA[8] + hA.w*wA[12];
    float m1 = hB.x*wB[0] + hB.y*wB[4] + hB.z*wB[8] + hB.w*wB[12];
    acc0 = fmaf(nm, m0, acc0);
    acc1 = fmaf(nm, m1, acc1);
    pl = nx;
  }
  agg[wid*HD + lane]      = acc0;
  agg[wid*HD + 64 + lane] = acc1;
}

__global__ __launch_bounds__(256)
void k_edge2(const int* __restrict__ row_ptr, const int4* __restrict__ pay,
             const float* __restrict__ h, const float* __restrict__ W,
             float* __restrict__ agg, int Nn){
  int wid = (blockIdx.x*256 + threadIdx.x)>>6;
  int lane = threadIdx.x & 63;
  if (wid >= Nn) return;
  int e0 = row_ptr[wid], e1 = row_ptr[wid+1];
  int ob = lane>>3, o = lane&7;
  float acc[4] = {0.f,0.f,0.f,0.f};
  int4 pl;
  if (e0 < e1) pl = pay[e0];
  for (int e=e0; e<e1; ++e){
    int4 nx = (e+1<e1) ? pay[e+1] : pl;
    int s = pl.x; int r = pl.y; float nm = __int_as_float(pl.z);
    const float* hp = &h[s*HD];
    const float* w  = &W[r*1024];
    #pragma unroll
    for (int u=0; u<4; ++u){
      int b = ob + 8*u;
      float4 hv = *(const float4*)&hp[b*4];
      const float* wc = &w[b*32 + o];
      float m = hv.x*wc[0] + hv.y*wc[8] + hv.z*wc[16] + hv.w*wc[24];
      acc[u] = fmaf(nm, m, acc[u]);
    }
    pl = nx;
  }
  #pragma unroll
  for (int u=0; u<4; ++u) agg[wid*256 + u*64 + lane] = acc[u];
}

// ---------------- fused self-loop GEMM + epilogue ----------------
// BM=128 rows/block, 128 local cols/block, 256 threads, 8x8 per-thread tile.
// Inner loop per kk: 2 A ds_read_b128 + 2 B ds_read_b128 -> 128 FMAs.
// As stored k-major (stride 132: 16B-aligned rows, <=2-way banks).
// EPI=1: out = relu(C + agg + bias)                    (NO=128, 1 block-col)
// EPI=2: NO=256 split into 2 strips; strip bx owns m-cols [bx*64,+64) and
//        hp-cols [128+bx*64,+64) so the gaussian epilogue stays thread-local.
template<int EPI>
__device__ __forceinline__ void gemm_body(const float* __restrict__ A,
                  const float* __restrict__ W,
                  const float* __restrict__ agg, const float* __restrict__ bias,
                  const float* __restrict__ eps, float* __restrict__ out,
                  int M, int rowBase, int bx){
  constexpr int NO = (EPI==1) ? 128 : 256;
  __shared__ __align__(16) float As[32*132];
  __shared__ __align__(16) float Bs[32*132];
  const int tid = threadIdx.x;
  const int cg = tid & 15, rg = tid >> 4;   // cols cg*4+64g, rows rg*8+i
  float acc[8][2][4];
  #pragma unroll
  for (int i=0;i<8;++i)
    #pragma unroll
    for (int g=0;g<2;++g)
      #pragma unroll
      for (int j=0;j<4;++j) acc[i][g][j]=0.f;

  for (int kt=0; kt<4; ++kt){
    // stage A tile transposed: 128 rows x 32 k  (1024 float4, 4/thread)
    #pragma unroll
    for (int it=0; it<4; ++it){
      int idx = it*256 + tid;
      int ar = idx>>3, ac4 = idx&7;
      int gr = rowBase + ar;
      F4 v; v.v = make_float4(0.f,0.f,0.f,0.f);
      if (gr < M) v.v = *(const float4*)&A[gr*HD + kt*32 + ac4*4];
      #pragma unroll
      for (int j=0;j<4;++j) As[(ac4*4+j)*132 + ar] = v.f[j];
    }
    // stage B tile: 32 k-rows x 128 local cols
    #pragma unroll
    for (int it=0; it<4; ++it){
      int idx = it*256 + tid;
      int wr = idx>>5, wc4 = idx&31;
      int gcol = (EPI==1) ? wc4*4
               : ((wc4<16) ? bx*64 + wc4*4 : 128 + bx*64 + (wc4-16)*4);
      *(float4*)&Bs[wr*132 + wc4*4] = *(const float4*)&W[(kt*32+wr)*NO + gcol];
    }
    __syncthreads();
    #pragma unroll 8
    for (int kk=0; kk<32; ++kk){
      F4 a0, a1, b0, b1;
      a0.v = *(const float4*)&As[kk*132 + rg*8];
      a1.v = *(const float4*)&As[kk*132 + rg*8 + 4];
      b0.v = *(const float4*)&Bs[kk*132 + cg*4];
      b1.v = *(const float4*)&Bs[kk*132 + cg*4 + 64];
      #pragma unroll
      for (int i=0;i<4;++i)
        #pragma unroll
        for (int j=0;j<4;++j){
          acc[i][0][j]   = fmaf(a0.f[i], b0.f[j], acc[i][0][j]);
          acc[i][1][j]   = fmaf(a0.f[i], b1.f[j], acc[i][1][j]);
          acc[i+4][0][j] = fmaf(a1.f[i], b0.f[j], acc[i+4][0][j]);
          acc[i+4][1][j] = fmaf(a1.f[i], b1.f[j], acc[i+4][1][j]);
        }
    }
    __syncthreads();
  }

  #pragma unroll
  for (int i=0;i<8;++i){
    int r = rowBase + rg*8 + i;
    if (r >= M) continue;
    if (EPI==1){
      #pragma unroll
      for (int g=0;g<2;++g){
        int col0 = cg*4 + 64*g;
        F4 ag; ag.v = *(const float4*)&agg[r*128 + col0];
        F4 bs; bs.v = *(const float4*)&bias[col0];
        F4 o;
        #pragma unroll
        for (int j=0;j<4;++j) o.f[j] = fmaxf(acc[i][g][j] + ag.f[j] + bs.f[j], 0.f);
        *(float4*)&out[r*128 + col0] = o.v;
      }
    } else {
      int colm = bx*64 + cg*4;           // m column (also eps/out column)
      F4 agm;  agm.v  = *(const float4*)&agg[r*256 + colm];
      F4 aghp; aghp.v = *(const float4*)&agg[r*256 + colm + 128];
      F4 bsm;  bsm.v  = *(const float4*)&bias[colm];
      F4 bshp; bshp.v = *(const float4*)&bias[colm + 128];
      F4 ep;   ep.v   = *(const float4*)&eps[r*128 + colm];
      F4 z;
      #pragma unroll
      for (int j=0;j<4;++j){
        float m  = acc[i][0][j] + agm.f[j]  + bsm.f[j];
        float hp = acc[i][1][j] + aghp.f[j] + bshp.f[j];
        float sp = fmaxf(hp, 0.f) + log1pf(expf(-fabsf(hp)));  // stable softplus
        z.f[j] = fmaf(sqrtf(sp + 1e-8f), ep.f[j], m);
      }
      *(float4*)&out[r*128 + colm] = z.v;
    }
  }
}

__global__ __launch_bounds__(256, 4)
void k_gemm_relu(const float* __restrict__ A, const float* __restrict__ W,
                 const float* __restrict__ agg, const float* __restrict__ bias,
                 float* __restrict__ out, int M){
  gemm_body<1>(A, W, agg, bias, nullptr, out, M, blockIdx.x*128, 0);
}

__global__ __launch_bounds__(256, 4)
void k_gemm_gauss(const float* __restrict__ A, const float* __restrict__ W,
                  const float* __restrict__ agg, const float* __restrict__ bias,
                  const float* __restrict__ eps, float* __restrict__ out, int M){
  gemm_body<2>(A, W, agg, bias, eps, out, M, (blockIdx.x>>1)*128, blockIdx.x&1);
}

extern "C" void kernel_launch(void* const* d_in, const int* in_sizes, int n_in,
                              void* d_out, int out_size, void* d_ws, size_t ws_size,
                              hipStream_t stream){
  (void)n_in; (void)out_size; (void)ws_size;
  const int*   node_ids = (const int*)d_in[0];
  const int*   src  = (const int*)d_in[1];
  const int*   dst  = (const int*)d_in[2];
  const int*   et   = (const int*)d_in[3];
  const float* norm = (const float*)d_in[4];
  const float* emb  = (const float*)d_in[5];
  const float* W1   = (const float*)d_in[6];
  const float* lw1  = (const float*)d_in[7];
  const float* b1   = (const float*)d_in[8];
  const float* W2   = (const float*)d_in[9];
  const float* lw2  = (const float*)d_in[10];
  const float* b2   = (const float*)d_in[11];
  const float* eps  = (const float*)d_in[12];
  float* out = (float*)d_out;

  const int N = in_sizes[0];
  const int E = in_sizes[1];

  // workspace layout (bytes):
  // [0, 2*szNH)        : h0 (first szNH; dead after gemm1) / agg2 (full 2*szNH)
  // [2*szNH, 3*szNH)   : h1
  // [3*szNH, 4*szNH)   : agg1
  // [4*szNH, ...)      : payload (int4, 16B-aligned) then CSR integer scratch
  char* w = (char*)d_ws;
  size_t szNH = (size_t)N*HD*sizeof(float);
  float* h0   = (float*)(w);
  float* agg2 = (float*)(w);
  float* h1   = (float*)(w + 2*szNH);
  float* agg1 = (float*)(w + 3*szNH);
  char*  ip   = w + 4*szNH;
  int4*  pay       = (int4*)ip;
  int*   counts    = (int*)(pay + E);
  int*   scanTmp   = counts + N;
  int*   row_ptr   = scanTmp + N;
  int*   cursors   = row_ptr + (N+1);
  int*   blockSums = cursors + N;

  hipMemsetAsync(counts, 0, (size_t)N*sizeof(int), stream);

  int nb_e    = (E+255)/256;
  int nb_scan = (N+255)/256;   // 391 (<1024, single-level top scan ok)

  k_gather<<<(N*32+255)/256, 256, 0, stream>>>(node_ids, (const float4*)emb, (float4*)h0, N*32);
  k_count<<<nb_e, 256, 0, stream>>>(dst, counts, E);
  k_scan_block<<<nb_scan, 256, 0, stream>>>(counts, scanTmp, blockSums, N);
  k_scan_top<<<1, 1024, 0, stream>>>(blockSums, nb_scan);
  k_scan_fin<<<nb_scan, 256, 0, stream>>>(scanTmp, blockSums, counts, row_ptr, cursors, N);
  k_scatter<<<nb_e, 256, 0, stream>>>(dst, src, et, norm, cursors, pay, E);

  int nb_rows = (N+3)/4;        // one 64-lane wave per dst row, 4 waves/block
  int nb_g    = (N+127)/128;    // 782 row-blocks

  k_edge1<<<nb_rows, 256, 0, stream>>>(row_ptr, pay, h0, W1, agg1, N);
  k_gemm_relu<<<nb_g, 256, 0, stream>>>(h0, lw1, agg1, b1, h1, N);
  k_edge2<<<nb_rows, 256, 0, stream>>>(row_ptr, pay, h1, W2, agg2, N);
  k_gemm_gauss<<<nb_g*2, 256, 0, stream>>>(h1, lw2, agg2, b2, eps, out, N);
}

// Round 6
// 518.713 us; speedup vs baseline: 1.2405x; 1.2405x over previous
//
#include <hip/hip_runtime.h>
#include <math.h>

#define HD 128

union F4 { float4 v; float f[4]; };

__device__ __forceinline__ float dot4(const F4& a, const F4& b){
  return fmaf(a.f[0], b.f[0], fmaf(a.f[1], b.f[1], fmaf(a.f[2], b.f[2], a.f[3]*b.f[3])));
}

// ---------------- CSR build ----------------
__global__ void k_count(const int* __restrict__ dst, int* __restrict__ counts, int E){
  int e = blockIdx.x*256 + threadIdx.x;
  if (e < E) atomicAdd(&counts[dst[e]], 1);
}

__global__ void k_scan_block(const int* __restrict__ counts, int* __restrict__ scanTmp,
                             int* __restrict__ blockSums, int n){
  __shared__ int sm[256];
  int i = blockIdx.x*256 + threadIdx.x;
  int v = (i<n)?counts[i]:0;
  sm[threadIdx.x]=v; __syncthreads();
  for (int ofs=1; ofs<256; ofs<<=1){
    int t = (threadIdx.x>=ofs)?sm[threadIdx.x-ofs]:0;
    __syncthreads();
    sm[threadIdx.x]+=t;
    __syncthreads();
  }
  if (i<n) scanTmp[i]=sm[threadIdx.x];
  if (threadIdx.x==255) blockSums[blockIdx.x]=sm[255];
}

__global__ void k_scan_top(int* __restrict__ blockSums, int nb){
  __shared__ int sm[1024];
  int v = ((int)threadIdx.x<nb)?blockSums[threadIdx.x]:0;
  sm[threadIdx.x]=v; __syncthreads();
  for (int ofs=1; ofs<1024; ofs<<=1){
    int t = ((int)threadIdx.x>=ofs)?sm[threadIdx.x-ofs]:0;
    __syncthreads();
    sm[threadIdx.x]+=t;
    __syncthreads();
  }
  if ((int)threadIdx.x<nb) blockSums[threadIdx.x] = sm[threadIdx.x]-v; // exclusive
}

__global__ void k_scan_fin(const int* __restrict__ scanTmp, const int* __restrict__ blockSums,
                           const int* __restrict__ counts,
                           int* __restrict__ row_ptr, int* __restrict__ cursors, int n){
  int i = blockIdx.x*256 + threadIdx.x;
  if (i<n){
    int incl = scanTmp[i] + blockSums[blockIdx.x];
    row_ptr[i+1] = incl;
    cursors[i] = incl - counts[i];
  }
  if (i==0) row_ptr[0]=0;
}

// scatter edges into CSR order, payload packed {src, etype, norm_bits, 0}
__global__ void k_scatter(const int* __restrict__ dst, const int* __restrict__ src,
                          const int* __restrict__ et, const float* __restrict__ norm,
                          int* __restrict__ cursors, int4* __restrict__ pay, int E){
  int e = blockIdx.x*256 + threadIdx.x;
  if (e<E){
    int p = atomicAdd(&cursors[dst[e]],1);
    pay[p] = make_int4(src[e], et[e], __float_as_int(norm[e]), 0);
  }
}

// ---------------- weight transposes: (rb, i, o) -> (rb, o, i) ----------------
// so each lane's weight column is a contiguous float4.
__global__ void k_w1t(const float* __restrict__ W, float* __restrict__ WT, int n){
  int d = blockIdx.x*256 + threadIdx.x;       // dest idx: rb*16 + o*4 + i
  if (d < n){
    int i = d & 3, o = (d>>2) & 3, rb = d>>4;
    WT[d] = W[rb*16 + i*4 + o];
  }
}
__global__ void k_w2t(const float* __restrict__ W, float* __restrict__ WT, int n){
  int d = blockIdx.x*256 + threadIdx.x;       // dest idx: rb*32 + o*4 + i
  if (d < n){
    int i = d & 3, o = (d>>2) & 7, rb = d>>5;
    WT[d] = W[rb*32 + i*8 + o];
  }
}

// ---------------- gather h0 = emb[node_ids] ----------------
__global__ void k_gather(const int* __restrict__ ids, const float4* __restrict__ emb4,
                         float4* __restrict__ h0, int nf4){
  int i = blockIdx.x*256+threadIdx.x;
  if (i<nf4){
    int row = i>>5, c = i&31;
    h0[i] = emb4[ids[row]*32 + c];
  }
}

// ---------------- edge aggregation (gather-CSR, one wave per dst row) ----------------
// wid is wave-uniform; readfirstlane makes that explicit so row_ptr and the
// payload records go through the SCALAR cache (s_load_dwordx4, lgkmcnt pipe),
// off the saturated VMEM path. Unrolled x2 over edges, loads batched first.
__global__ __launch_bounds__(256)
void k_edge1(const int* __restrict__ row_ptr, const int4* __restrict__ pay,
             const float* __restrict__ h, const float* __restrict__ WT,
             float* __restrict__ agg, int Nn){
  int wid = (blockIdx.x*256 + threadIdx.x)>>6;
  wid = __builtin_amdgcn_readfirstlane(wid);
  int lane = threadIdx.x & 63;
  if (wid >= Nn) return;
  int e0 = row_ptr[wid], e1 = row_ptr[wid+1];
  int b0 = lane>>2, o = lane&3;
  float acc0=0.f, acc1=0.f;
  for (int e=e0; e<e1; e+=2){
    int4 p0 = pay[e];
    bool has2 = (e+1 < e1);
    int4 p1 = has2 ? pay[e+1] : p0;
    float n0 = __int_as_float(p0.z);
    float n1 = has2 ? __int_as_float(p1.z) : 0.f;
    const float* ha = &h[p0.x*HD];  const float* wa = &WT[p0.y*512];
    const float* hb = &h[p1.x*HD];  const float* wb = &WT[p1.y*512];
    F4 hA0,hB0,wA0,wB0,hA1,hB1,wA1,wB1;
    hA0.v = *(const float4*)&ha[b0*4];
    hB0.v = *(const float4*)&ha[(b0+16)*4];
    wA0.v = *(const float4*)&wa[b0*16 + o*4];
    wB0.v = *(const float4*)&wa[(b0+16)*16 + o*4];
    hA1.v = *(const float4*)&hb[b0*4];
    hB1.v = *(const float4*)&hb[(b0+16)*4];
    wA1.v = *(const float4*)&wb[b0*16 + o*4];
    wB1.v = *(const float4*)&wb[(b0+16)*16 + o*4];
    acc0 = fmaf(n0, dot4(hA0,wA0), acc0);
    acc1 = fmaf(n0, dot4(hB0,wB0), acc1);
    acc0 = fmaf(n1, dot4(hA1,wA1), acc0);
    acc1 = fmaf(n1, dot4(hB1,wB1), acc1);
  }
  agg[wid*HD + lane]      = acc0;
  agg[wid*HD + 64 + lane] = acc1;
}

__global__ __launch_bounds__(256)
void k_edge2(const int* __restrict__ row_ptr, const int4* __restrict__ pay,
             const float* __restrict__ h, const float* __restrict__ WT,
             float* __restrict__ agg, int Nn){
  int wid = (blockIdx.x*256 + threadIdx.x)>>6;
  wid = __builtin_amdgcn_readfirstlane(wid);
  int lane = threadIdx.x & 63;
  if (wid >= Nn) return;
  int e0 = row_ptr[wid], e1 = row_ptr[wid+1];
  int ob = lane>>3, o = lane&7;
  float acc[4] = {0.f,0.f,0.f,0.f};
  for (int e=e0; e<e1; e+=2){
    int4 p0 = pay[e];
    bool has2 = (e+1 < e1);
    int4 p1 = has2 ? pay[e+1] : p0;
    float n0 = __int_as_float(p0.z);
    float n1 = has2 ? __int_as_float(p1.z) : 0.f;
    const float* ha = &h[p0.x*HD];  const float* wa = &WT[p0.y*1024];
    const float* hb = &h[p1.x*HD];  const float* wb = &WT[p1.y*1024];
    F4 hva[4], wva[4], hvb[4], wvb[4];
    #pragma unroll
    for (int u=0; u<4; ++u){
      int b = ob + 8*u;
      hva[u].v = *(const float4*)&ha[b*4];
      wva[u].v = *(const float4*)&wa[b*32 + o*4];
      hvb[u].v = *(const float4*)&hb[b*4];
      wvb[u].v = *(const float4*)&wb[b*32 + o*4];
    }
    #pragma unroll
    for (int u=0; u<4; ++u){
      acc[u] = fmaf(n0, dot4(hva[u],wva[u]), acc[u]);
      acc[u] = fmaf(n1, dot4(hvb[u],wvb[u]), acc[u]);
    }
  }
  #pragma unroll
  for (int u=0; u<4; ++u) agg[wid*256 + u*64 + lane] = acc[u];
}

// ---------------- fused self-loop GEMM + epilogue ----------------
// BM=128 rows/block, 128 local cols/block, 256 threads, 8x8 per-thread tile.
// Inner loop per kk: 2 A ds_read_b128 + 2 B ds_read_b128 -> 128 FMAs.
// As stored k-major (stride 132: 16B-aligned rows, <=2-way banks).
// EPI=1: out = relu(C + agg + bias)                    (NO=128, 1 block-col)
// EPI=2: NO=256 split into 2 strips; strip bx owns m-cols [bx*64,+64) and
//        hp-cols [128+bx*64,+64) so the gaussian epilogue stays thread-local.
template<int EPI>
__device__ __forceinline__ void gemm_body(const float* __restrict__ A,
                  const float* __restrict__ W,
                  const float* __restrict__ agg, const float* __restrict__ bias,
                  const float* __restrict__ eps, float* __restrict__ out,
                  int M, int rowBase, int bx){
  constexpr int NO = (EPI==1) ? 128 : 256;
  __shared__ __align__(16) float As[32*132];
  __shared__ __align__(16) float Bs[32*132];
  const int tid = threadIdx.x;
  const int cg = tid & 15, rg = tid >> 4;   // cols cg*4+64g, rows rg*8+i
  float acc[8][2][4];
  #pragma unroll
  for (int i=0;i<8;++i)
    #pragma unroll
    for (int g=0;g<2;++g)
      #pragma unroll
      for (int j=0;j<4;++j) acc[i][g][j]=0.f;

  for (int kt=0; kt<4; ++kt){
    // stage A tile transposed: 128 rows x 32 k  (1024 float4, 4/thread)
    #pragma unroll
    for (int it=0; it<4; ++it){
      int idx = it*256 + tid;
      int ar = idx>>3, ac4 = idx&7;
      int gr = rowBase + ar;
      F4 v; v.v = make_float4(0.f,0.f,0.f,0.f);
      if (gr < M) v.v = *(const float4*)&A[gr*HD + kt*32 + ac4*4];
      #pragma unroll
      for (int j=0;j<4;++j) As[(ac4*4+j)*132 + ar] = v.f[j];
    }
    // stage B tile: 32 k-rows x 128 local cols
    #pragma unroll
    for (int it=0; it<4; ++it){
      int idx = it*256 + tid;
      int wr = idx>>5, wc4 = idx&31;
      int gcol = (EPI==1) ? wc4*4
               : ((wc4<16) ? bx*64 + wc4*4 : 128 + bx*64 + (wc4-16)*4);
      *(float4*)&Bs[wr*132 + wc4*4] = *(const float4*)&W[(kt*32+wr)*NO + gcol];
    }
    __syncthreads();
    #pragma unroll 8
    for (int kk=0; kk<32; ++kk){
      F4 a0, a1, b0, b1;
      a0.v = *(const float4*)&As[kk*132 + rg*8];
      a1.v = *(const float4*)&As[kk*132 + rg*8 + 4];
      b0.v = *(const float4*)&Bs[kk*132 + cg*4];
      b1.v = *(const float4*)&Bs[kk*132 + cg*4 + 64];
      #pragma unroll
      for (int i=0;i<4;++i)
        #pragma unroll
        for (int j=0;j<4;++j){
          acc[i][0][j]   = fmaf(a0.f[i], b0.f[j], acc[i][0][j]);
          acc[i][1][j]   = fmaf(a0.f[i], b1.f[j], acc[i][1][j]);
          acc[i+4][0][j] = fmaf(a1.f[i], b0.f[j], acc[i+4][0][j]);
          acc[i+4][1][j] = fmaf(a1.f[i], b1.f[j], acc[i+4][1][j]);
        }
    }
    __syncthreads();
  }

  #pragma unroll
  for (int i=0;i<8;++i){
    int r = rowBase + rg*8 + i;
    if (r >= M) continue;
    if (EPI==1){
      #pragma unroll
      for (int g=0;g<2;++g){
        int col0 = cg*4 + 64*g;
        F4 ag; ag.v = *(const float4*)&agg[r*128 + col0];
        F4 bs; bs.v = *(const float4*)&bias[col0];
        F4 o;
        #pragma unroll
        for (int j=0;j<4;++j) o.f[j] = fmaxf(acc[i][g][j] + ag.f[j] + bs.f[j], 0.f);
        *(float4*)&out[r*128 + col0] = o.v;
      }
    } else {
      int colm = bx*64 + cg*4;           // m column (also eps/out column)
      F4 agm;  agm.v  = *(const float4*)&agg[r*256 + colm];
      F4 aghp; aghp.v = *(const float4*)&agg[r*256 + colm + 128];
      F4 bsm;  bsm.v  = *(const float4*)&bias[colm];
      F4 bshp; bshp.v = *(const float4*)&bias[colm + 128];
      F4 ep;   ep.v   = *(const float4*)&eps[r*128 + colm];
      F4 z;
      #pragma unroll
      for (int j=0;j<4;++j){
        float m  = acc[i][0][j] + agm.f[j]  + bsm.f[j];
        float hp = acc[i][1][j] + aghp.f[j] + bshp.f[j];
        float sp = fmaxf(hp, 0.f) + log1pf(expf(-fabsf(hp)));  // stable softplus
        z.f[j] = fmaf(sqrtf(sp + 1e-8f), ep.f[j], m);
      }
      *(float4*)&out[r*128 + colm] = z.v;
    }
  }
}

__global__ __launch_bounds__(256, 4)
void k_gemm_relu(const float* __restrict__ A, const float* __restrict__ W,
                 const float* __restrict__ agg, const float* __restrict__ bias,
                 float* __restrict__ out, int M){
  gemm_body<1>(A, W, agg, bias, nullptr, out, M, blockIdx.x*128, 0);
}

__global__ __launch_bounds__(256, 4)
void k_gemm_gauss(const float* __restrict__ A, const float* __restrict__ W,
                  const float* __restrict__ agg, const float* __restrict__ bias,
                  const float* __restrict__ eps, float* __restrict__ out, int M){
  gemm_body<2>(A, W, agg, bias, eps, out, M, (blockIdx.x>>1)*128, blockIdx.x&1);
}

extern "C" void kernel_launch(void* const* d_in, const int* in_sizes, int n_in,
                              void* d_out, int out_size, void* d_ws, size_t ws_size,
                              hipStream_t stream){
  (void)n_in; (void)out_size; (void)ws_size;
  const int*   node_ids = (const int*)d_in[0];
  const int*   src  = (const int*)d_in[1];
  const int*   dst  = (const int*)d_in[2];
  const int*   et   = (const int*)d_in[3];
  const float* norm = (const float*)d_in[4];
  const float* emb  = (const float*)d_in[5];
  const float* W1   = (const float*)d_in[6];
  const float* lw1  = (const float*)d_in[7];
  const float* b1   = (const float*)d_in[8];
  const float* W2   = (const float*)d_in[9];
  const float* lw2  = (const float*)d_in[10];
  const float* b2   = (const float*)d_in[11];
  const float* eps  = (const float*)d_in[12];
  float* out = (float*)d_out;

  const int N  = in_sizes[0];
  const int E  = in_sizes[1];
  const int n1 = in_sizes[6];    // R*B*4*4
  const int n2 = in_sizes[9];    // R*B*4*8

  // workspace layout (bytes):
  // [0, 2*szNH)        : h0 (first szNH; dead after gemm1) / agg2 (full 2*szNH)
  // [2*szNH, 3*szNH)   : h1
  // [3*szNH, 4*szNH)   : agg1
  // [4*szNH, ...)      : payload (int4) | CSR ints | W1T | W2T
  char* w = (char*)d_ws;
  size_t szNH = (size_t)N*HD*sizeof(float);
  float* h0   = (float*)(w);
  float* agg2 = (float*)(w);
  float* h1   = (float*)(w + 2*szNH);
  float* agg1 = (float*)(w + 3*szNH);
  char*  ip   = w + 4*szNH;
  int4*  pay       = (int4*)ip;
  int*   counts    = (int*)(pay + E);
  int*   scanTmp   = counts + N;
  int*   row_ptr   = scanTmp + N;
  int*   cursors   = row_ptr + (N+1);
  int*   blockSums = cursors + N;
  float* W1T       = (float*)(blockSums + 1024);
  float* W2T       = W1T + n1;

  hipMemsetAsync(counts, 0, (size_t)N*sizeof(int), stream);

  int nb_e    = (E+255)/256;
  int nb_scan = (N+255)/256;   // 391 (<1024, single-level top scan ok)

  k_w1t<<<(n1+255)/256, 256, 0, stream>>>(W1, W1T, n1);
  k_w2t<<<(n2+255)/256, 256, 0, stream>>>(W2, W2T, n2);
  k_gather<<<(N*32+255)/256, 256, 0, stream>>>(node_ids, (const float4*)emb, (float4*)h0, N*32);
  k_count<<<nb_e, 256, 0, stream>>>(dst, counts, E);
  k_scan_block<<<nb_scan, 256, 0, stream>>>(counts, scanTmp, blockSums, N);
  k_scan_top<<<1, 1024, 0, stream>>>(blockSums, nb_scan);
  k_scan_fin<<<nb_scan, 256, 0, stream>>>(scanTmp, blockSums, counts, row_ptr, cursors, N);
  k_scatter<<<nb_e, 256, 0, stream>>>(dst, src, et, norm, cursors, pay, E);

  int nb_rows = (N+3)/4;        // one 64-lane wave per dst row, 4 waves/block
  int nb_g    = (N+127)/128;    // 782 row-blocks

  k_edge1<<<nb_rows, 256, 0, stream>>>(row_ptr, pay, h0, W1T, agg1, N);
  k_gemm_relu<<<nb_g, 256, 0, stream>>>(h0, lw1, agg1, b1, h1, N);
  k_edge2<<<nb_rows, 256, 0, stream>>>(row_ptr, pay, h1, W2T, agg2, N);
  k_gemm_gauss<<<nb_g*2, 256, 0, stream>>>(h1, lw2, agg2, b2, eps, out, N);
}

// Round 7
// 430.482 us; speedup vs baseline: 1.4948x; 1.2050x over previous
//
#include <hip/hip_runtime.h>
#include <math.h>

#define HD 128

union F4 { float4 v; float f[4]; };

typedef __attribute__((ext_vector_type(8))) short bf8_t;   // 8 bf16 (4 VGPRs)
typedef __attribute__((ext_vector_type(4))) float f4_t;    // MFMA C/D

__device__ __forceinline__ float dot4(const F4& a, const F4& b){
  return fmaf(a.f[0], b.f[0], fmaf(a.f[1], b.f[1], fmaf(a.f[2], b.f[2], a.f[3]*b.f[3])));
}

__device__ __forceinline__ unsigned short f2bf(float f){   // RNE fp32->bf16
  unsigned int u = __float_as_uint(f);
  return (unsigned short)((u + 0x7fffu + ((u>>16)&1u)) >> 16);
}

// ---------------- CSR build ----------------
__global__ void k_count(const int* __restrict__ dst, int* __restrict__ counts, int E){
  int e = blockIdx.x*256 + threadIdx.x;
  if (e < E) atomicAdd(&counts[dst[e]], 1);
}

__global__ void k_scan_block(const int* __restrict__ counts, int* __restrict__ scanTmp,
                             int* __restrict__ blockSums, int n){
  __shared__ int sm[256];
  int i = blockIdx.x*256 + threadIdx.x;
  int v = (i<n)?counts[i]:0;
  sm[threadIdx.x]=v; __syncthreads();
  for (int ofs=1; ofs<256; ofs<<=1){
    int t = (threadIdx.x>=ofs)?sm[threadIdx.x-ofs]:0;
    __syncthreads();
    sm[threadIdx.x]+=t;
    __syncthreads();
  }
  if (i<n) scanTmp[i]=sm[threadIdx.x];
  if (threadIdx.x==255) blockSums[blockIdx.x]=sm[255];
}

__global__ void k_scan_top(int* __restrict__ blockSums, int nb){
  __shared__ int sm[1024];
  int v = ((int)threadIdx.x<nb)?blockSums[threadIdx.x]:0;
  sm[threadIdx.x]=v; __syncthreads();
  for (int ofs=1; ofs<1024; ofs<<=1){
    int t = ((int)threadIdx.x>=ofs)?sm[threadIdx.x-ofs]:0;
    __syncthreads();
    sm[threadIdx.x]+=t;
    __syncthreads();
  }
  if ((int)threadIdx.x<nb) blockSums[threadIdx.x] = sm[threadIdx.x]-v; // exclusive
}

__global__ void k_scan_fin(const int* __restrict__ scanTmp, const int* __restrict__ blockSums,
                           const int* __restrict__ counts,
                           int* __restrict__ row_ptr, int* __restrict__ cursors, int n){
  int i = blockIdx.x*256 + threadIdx.x;
  if (i<n){
    int incl = scanTmp[i] + blockSums[blockIdx.x];
    row_ptr[i+1] = incl;
    cursors[i] = incl - counts[i];
  }
  if (i==0) row_ptr[0]=0;
}

// scatter edges into CSR order, payload packed {src, etype, norm_bits, 0}
__global__ void k_scatter(const int* __restrict__ dst, const int* __restrict__ src,
                          const int* __restrict__ et, const float* __restrict__ norm,
                          int* __restrict__ cursors, int4* __restrict__ pay, int E){
  int e = blockIdx.x*256 + threadIdx.x;
  if (e<E){
    int p = atomicAdd(&cursors[dst[e]],1);
    pay[p] = make_int4(src[e], et[e], __float_as_int(norm[e]), 0);
  }
}

// ---------------- edge-weight transposes: (rb, i, o) -> (rb, o, i) ----------------
__global__ void k_w1t(const float* __restrict__ W, float* __restrict__ WT, int n){
  int d = blockIdx.x*256 + threadIdx.x;       // dest idx: rb*16 + o*4 + i
  if (d < n){
    int i = d & 3, o = (d>>2) & 3, rb = d>>4;
    WT[d] = W[rb*16 + i*4 + o];
  }
}
__global__ void k_w2t(const float* __restrict__ W, float* __restrict__ WT, int n){
  int d = blockIdx.x*256 + threadIdx.x;       // dest idx: rb*32 + o*4 + i
  if (d < n){
    int i = d & 3, o = (d>>2) & 7, rb = d>>5;
    WT[d] = W[rb*32 + i*8 + o];
  }
}

// ---------------- loop-weight pack to MFMA B-fragment layout (bf16) ----------------
// Wp[ct][ks][lane][j] = bf16( W[(ks*32 + (lane>>4)*8 + j)*NO + ct*16 + (lane&15)] )
// so a lane's 8 B-operand values are one contiguous 16B load.
__global__ void k_wpack(const float* __restrict__ W, unsigned short* __restrict__ Wp,
                        int NCT, int NO){
  int t = blockIdx.x*256 + threadIdx.x;
  if (t >= NCT*256) return;
  int lane = t & 63, ks = (t>>6) & 3, ct = t >> 8;
  int k0 = ks*32 + (lane>>4)*8, col = ct*16 + (lane&15);
  unsigned short v[8];
  #pragma unroll
  for (int j=0;j<8;++j) v[j] = f2bf(W[(k0+j)*NO + col]);
  ushort4* dst = (ushort4*)&Wp[(size_t)t*8];
  dst[0] = make_ushort4(v[0],v[1],v[2],v[3]);
  dst[1] = make_ushort4(v[4],v[5],v[6],v[7]);
}

// ---------------- gather h0 = emb[node_ids] (f32 + bf16 copies) ----------------
__global__ void k_gather(const int* __restrict__ ids, const float4* __restrict__ emb4,
                         float4* __restrict__ h0, unsigned short* __restrict__ h0b, int nf4){
  int i = blockIdx.x*256+threadIdx.x;
  if (i<nf4){
    int row = i>>5, c = i&31;
    float4 v = emb4[ids[row]*32 + c];
    h0[i] = v;
    *(ushort4*)&h0b[(size_t)i*4] = make_ushort4(f2bf(v.x),f2bf(v.y),f2bf(v.z),f2bf(v.w));
  }
}

// ---------------- edge aggregation (gather-CSR, one wave per dst row) ----------------
__global__ __launch_bounds__(256)
void k_edge1(const int* __restrict__ row_ptr, const int4* __restrict__ pay,
             const float* __restrict__ h, const float* __restrict__ WT,
             float* __restrict__ agg, int Nn){
  int wid = (blockIdx.x*256 + threadIdx.x)>>6;
  wid = __builtin_amdgcn_readfirstlane(wid);
  int lane = threadIdx.x & 63;
  if (wid >= Nn) return;
  int e0 = row_ptr[wid], e1 = row_ptr[wid+1];
  int b0 = lane>>2, o = lane&3;
  float acc0=0.f, acc1=0.f;
  for (int e=e0; e<e1; e+=2){
    int4 p0 = pay[e];
    bool has2 = (e+1 < e1);
    int4 p1 = has2 ? pay[e+1] : p0;
    float n0 = __int_as_float(p0.z);
    float n1 = has2 ? __int_as_float(p1.z) : 0.f;
    const float* ha = &h[p0.x*HD];  const float* wa = &WT[p0.y*512];
    const float* hb = &h[p1.x*HD];  const float* wb = &WT[p1.y*512];
    F4 hA0,hB0,wA0,wB0,hA1,hB1,wA1,wB1;
    hA0.v = *(const float4*)&ha[b0*4];
    hB0.v = *(const float4*)&ha[(b0+16)*4];
    wA0.v = *(const float4*)&wa[b0*16 + o*4];
    wB0.v = *(const float4*)&wa[(b0+16)*16 + o*4];
    hA1.v = *(const float4*)&hb[b0*4];
    hB1.v = *(const float4*)&hb[(b0+16)*4];
    wA1.v = *(const float4*)&wb[b0*16 + o*4];
    wB1.v = *(const float4*)&wb[(b0+16)*16 + o*4];
    acc0 = fmaf(n0, dot4(hA0,wA0), acc0);
    acc1 = fmaf(n0, dot4(hB0,wB0), acc1);
    acc0 = fmaf(n1, dot4(hA1,wA1), acc0);
    acc1 = fmaf(n1, dot4(hB1,wB1), acc1);
  }
  agg[wid*HD + lane]      = acc0;
  agg[wid*HD + 64 + lane] = acc1;
}

__global__ __launch_bounds__(256)
void k_edge2(const int* __restrict__ row_ptr, const int4* __restrict__ pay,
             const float* __restrict__ h, const float* __restrict__ WT,
             float* __restrict__ agg, int Nn){
  int wid = (blockIdx.x*256 + threadIdx.x)>>6;
  wid = __builtin_amdgcn_readfirstlane(wid);
  int lane = threadIdx.x & 63;
  if (wid >= Nn) return;
  int e0 = row_ptr[wid], e1 = row_ptr[wid+1];
  int ob = lane>>3, o = lane&7;
  float acc[4] = {0.f,0.f,0.f,0.f};
  for (int e=e0; e<e1; e+=2){
    int4 p0 = pay[e];
    bool has2 = (e+1 < e1);
    int4 p1 = has2 ? pay[e+1] : p0;
    float n0 = __int_as_float(p0.z);
    float n1 = has2 ? __int_as_float(p1.z) : 0.f;
    const float* ha = &h[p0.x*HD];  const float* wa = &WT[p0.y*1024];
    const float* hb = &h[p1.x*HD];  const float* wb = &WT[p1.y*1024];
    F4 hva[4], wva[4], hvb[4], wvb[4];
    #pragma unroll
    for (int u=0; u<4; ++u){
      int b = ob + 8*u;
      hva[u].v = *(const float4*)&ha[b*4];
      wva[u].v = *(const float4*)&wa[b*32 + o*4];
      hvb[u].v = *(const float4*)&hb[b*4];
      wvb[u].v = *(const float4*)&wb[b*32 + o*4];
    }
    #pragma unroll
    for (int u=0; u<4; ++u){
      acc[u] = fmaf(n0, dot4(hva[u],wva[u]), acc[u]);
      acc[u] = fmaf(n1, dot4(hvb[u],wvb[u]), acc[u]);
    }
  }
  #pragma unroll
  for (int u=0; u<4; ++u) agg[wid*256 + u*64 + lane] = acc[u];
}

// ---------------- MFMA self-loop GEMMs (bf16 in, fp32 accum) ----------------
// A-frag (16x16x32): lane holds A[row=lane&15][k=(lane>>4)*8+j]  -> 16B load from
// row-major bf16 A. B-frag from pre-packed Wp. C: col=lane&15, row=(lane>>4)*4+r
// (m89-verified). Wave = 16 rows x 128 cols = 8 ct x 4 ks = 32 MFMAs. No LDS.
__global__ __launch_bounds__(256)
void k_mfma_relu(const unsigned short* __restrict__ Ab, const unsigned short* __restrict__ Wp,
                 const float* __restrict__ agg, const float* __restrict__ bias,
                 float* __restrict__ out, unsigned short* __restrict__ outb, int M){
  const int lane = threadIdx.x & 63;
  const int rowBase = blockIdx.x*64 + (threadIdx.x>>6)*16;
  const int ar = lane & 15, kg = lane >> 4;
  const int aclamp = min(rowBase + ar, M-1);
  f4_t acc[8];
  #pragma unroll
  for (int ct=0; ct<8; ++ct) acc[ct] = (f4_t)0.f;
  #pragma unroll
  for (int ks=0; ks<4; ++ks){
    bf8_t a = *(const bf8_t*)&Ab[(size_t)aclamp*HD + ks*32 + kg*8];
    #pragma unroll
    for (int ct=0; ct<8; ++ct){
      bf8_t b = *(const bf8_t*)&Wp[(size_t)((ct*4 + ks)*64 + lane)*8];
      acc[ct] = __builtin_amdgcn_mfma_f32_16x16x32_bf16(a, b, acc[ct], 0,0,0);
    }
  }
  const int crow = rowBase + kg*4;
  #pragma unroll
  for (int r=0; r<4; ++r){
    int gr = crow + r;
    if (gr >= M) continue;
    #pragma unroll
    for (int ct=0; ct<8; ++ct){
      int col = ct*16 + ar;
      float v = fmaxf(acc[ct][r] + agg[(size_t)gr*128 + col] + bias[col], 0.f);
      out[(size_t)gr*128 + col] = v;
      outb[(size_t)gr*128 + col] = f2bf(v);
    }
  }
}

// gauss: NO=256; strip bx owns m-cols [bx*64,+64) and hp-cols [128+bx*64,+64)
__global__ __launch_bounds__(256)
void k_mfma_gauss(const unsigned short* __restrict__ Ab, const unsigned short* __restrict__ Wp,
                  const float* __restrict__ agg, const float* __restrict__ bias,
                  const float* __restrict__ eps, float* __restrict__ out, int M){
  const int lane = threadIdx.x & 63;
  const int bx = blockIdx.x & 1;
  const int rowBase = (blockIdx.x>>1)*64 + (threadIdx.x>>6)*16;
  const int ar = lane & 15, kg = lane >> 4;
  const int aclamp = min(rowBase + ar, M-1);
  f4_t accm[4], acch[4];
  #pragma unroll
  for (int ct=0; ct<4; ++ct){ accm[ct] = (f4_t)0.f; acch[ct] = (f4_t)0.f; }
  #pragma unroll
  for (int ks=0; ks<4; ++ks){
    bf8_t a = *(const bf8_t*)&Ab[(size_t)aclamp*HD + ks*32 + kg*8];
    #pragma unroll
    for (int ct=0; ct<4; ++ct){
      int ctm = bx*4 + ct, cth = 8 + bx*4 + ct;
      bf8_t bm = *(const bf8_t*)&Wp[(size_t)((ctm*4 + ks)*64 + lane)*8];
      bf8_t bh = *(const bf8_t*)&Wp[(size_t)((cth*4 + ks)*64 + lane)*8];
      accm[ct] = __builtin_amdgcn_mfma_f32_16x16x32_bf16(a, bm, accm[ct], 0,0,0);
      acch[ct] = __builtin_amdgcn_mfma_f32_16x16x32_bf16(a, bh, acch[ct], 0,0,0);
    }
  }
  const int crow = rowBase + kg*4;
  #pragma unroll
  for (int r=0; r<4; ++r){
    int gr = crow + r;
    if (gr >= M) continue;
    #pragma unroll
    for (int ct=0; ct<4; ++ct){
      int colm = bx*64 + ct*16 + ar;
      float m  = accm[ct][r] + agg[(size_t)gr*256 + colm]       + bias[colm];
      float hp = acch[ct][r] + agg[(size_t)gr*256 + colm + 128] + bias[colm+128];
      float sp = fmaxf(hp, 0.f) + log1pf(expf(-fabsf(hp)));  // stable softplus
      out[(size_t)gr*128 + colm] = fmaf(sqrtf(sp + 1e-8f), eps[(size_t)gr*128 + colm], m);
    }
  }
}

extern "C" void kernel_launch(void* const* d_in, const int* in_sizes, int n_in,
                              void* d_out, int out_size, void* d_ws, size_t ws_size,
                              hipStream_t stream){
  (void)n_in; (void)out_size; (void)ws_size;
  const int*   node_ids = (const int*)d_in[0];
  const int*   src  = (const int*)d_in[1];
  const int*   dst  = (const int*)d_in[2];
  const int*   et   = (const int*)d_in[3];
  const float* norm = (const float*)d_in[4];
  const float* emb  = (const float*)d_in[5];
  const float* W1   = (const float*)d_in[6];
  const float* lw1  = (const float*)d_in[7];
  const float* b1   = (const float*)d_in[8];
  const float* W2   = (const float*)d_in[9];
  const float* lw2  = (const float*)d_in[10];
  const float* b2   = (const float*)d_in[11];
  const float* eps  = (const float*)d_in[12];
  float* out = (float*)d_out;

  const int N  = in_sizes[0];
  const int E  = in_sizes[1];
  const int n1 = in_sizes[6];    // R*B*4*4
  const int n2 = in_sizes[9];    // R*B*4*8

  // workspace layout (bytes):
  // [0, 2*szNH)        : h0 (first szNH; dead after gemm1) / agg2 (full 2*szNH)
  // [2*szNH, 3*szNH)   : h1 (f32)
  // [3*szNH, 4*szNH)   : agg1
  // then: pay | CSR ints | W1T | W2T | W1p | W2p | h0b | h1b  (16B-aligned tail)
  char* w = (char*)d_ws;
  size_t szNH = (size_t)N*HD*sizeof(float);
  float* h0   = (float*)(w);
  float* agg2 = (float*)(w);
  float* h1   = (float*)(w + 2*szNH);
  float* agg1 = (float*)(w + 3*szNH);
  char*  ip   = w + 4*szNH;
  int4*  pay       = (int4*)ip;
  int*   counts    = (int*)(pay + E);
  int*   scanTmp   = counts + N;
  int*   row_ptr   = scanTmp + N;
  int*   cursors   = row_ptr + (N+1);
  int*   blockSums = cursors + N;
  float* W1T       = (float*)(blockSums + 1024);
  float* W2T       = W1T + n1;
  size_t tail      = ((size_t)((char*)(W2T + n2) - w) + 63) & ~(size_t)63;
  unsigned short* W1p = (unsigned short*)(w + tail);            //  8*256*8 = 16384
  unsigned short* W2p = W1p + 8*256*8;                          // 16*256*8 = 32768
  unsigned short* h0b = W2p + 16*256*8;
  unsigned short* h1b = h0b + (size_t)N*HD;

  hipMemsetAsync(counts, 0, (size_t)N*sizeof(int), stream);

  int nb_e    = (E+255)/256;
  int nb_scan = (N+255)/256;

  k_w1t<<<(n1+255)/256, 256, 0, stream>>>(W1, W1T, n1);
  k_w2t<<<(n2+255)/256, 256, 0, stream>>>(W2, W2T, n2);
  k_wpack<<<8, 256, 0, stream>>>(lw1, W1p, 8, 128);
  k_wpack<<<16, 256, 0, stream>>>(lw2, W2p, 16, 256);
  k_gather<<<(N*32+255)/256, 256, 0, stream>>>(node_ids, (const float4*)emb, (float4*)h0, h0b, N*32);
  k_count<<<nb_e, 256, 0, stream>>>(dst, counts, E);
  k_scan_block<<<nb_scan, 256, 0, stream>>>(counts, scanTmp, blockSums, N);
  k_scan_top<<<1, 1024, 0, stream>>>(blockSums, nb_scan);
  k_scan_fin<<<nb_scan, 256, 0, stream>>>(scanTmp, blockSums, counts, row_ptr, cursors, N);
  k_scatter<<<nb_e, 256, 0, stream>>>(dst, src, et, norm, cursors, pay, E);

  int nb_rows = (N+3)/4;        // one 64-lane wave per dst row, 4 waves/block
  int nb_m    = (N+63)/64;      // 64 rows per MFMA block

  k_edge1<<<nb_rows, 256, 0, stream>>>(row_ptr, pay, h0, W1T, agg1, N);
  k_mfma_relu<<<nb_m, 256, 0, stream>>>(h0b, W1p, agg1, b1, h1, h1b, N);
  k_edge2<<<nb_rows, 256, 0, stream>>>(row_ptr, pay, h1, W2T, agg2, N);
  k_mfma_gauss<<<nb_m*2, 256, 0, stream>>>(h1b, W2p, agg2, b2, eps, out, N);
}